// Round 14
// baseline (185.307 us; speedup 1.0000x reference)
//
#include <hip/hip_runtime.h>
#include <math.h>

#define B_ 16
#define N_ 16384
#define C_ 256
#define H_ 128
#define K_ 11468   // int(16384 * 0.7)
#define G_ ((B_ * N_) / 16)   // 16384 groups of 16 tokens
#define GPB_ 16               // groups per block
#define NBLK_ (G_ / GPB_)     // 1024 blocks

typedef __attribute__((ext_vector_type(8))) short s16x8;
typedef __attribute__((ext_vector_type(4))) float f32x4;
typedef __attribute__((ext_vector_type(4))) unsigned int u32x4;

__device__ __forceinline__ unsigned short f2bf(float f) {
  unsigned u = __builtin_bit_cast(unsigned, f);
  return (unsigned short)((u + 0x7FFFu + ((u >> 16) & 1u)) >> 16);  // RNE
}
// order-preserving map fp32 -> uint32 (no NaNs expected)
__device__ __forceinline__ unsigned fkey(float f) {
  unsigned u = __builtin_bit_cast(unsigned, f);
  return (u & 0x80000000u) ? ~u : (u | 0x80000000u);
}
// pack two fp32 to two bf16 (truncation) in one v_perm — same bits as rounds 4-13
__device__ __forceinline__ unsigned pk2(float hi, float lo) {
  return __builtin_amdgcn_perm(__builtin_bit_cast(unsigned, hi),
                               __builtin_bit_cast(unsigned, lo), 0x07060302u);
}

// branch-free GELU: Winitzki erf approx (max abs err ~1.2e-4), ~14 VALU ops.
__device__ __forceinline__ float gelu_fast(float h) {
  const float t = 0.5f * h * h;                 // z^2, z = h/sqrt(2)
  const float u = 0.147f * t;
  const float num = t * (1.2732395f + u);       // z^2*(4/pi + a z^2)
  const float den = 1.0f + u;
  const float r = num * __builtin_amdgcn_rcpf(den);
  const float e = __builtin_amdgcn_exp2f(r * -1.44269504f);   // exp(-r)
  const float s = __builtin_amdgcn_sqrtf(fmaxf(1.0f - e, 0.0f));
  const unsigned sgn = __builtin_bit_cast(unsigned, h) & 0x80000000u;
  const float erfv = __builtin_bit_cast(float, __builtin_bit_cast(unsigned, s) | sgn);
  return 0.5f * h * (1.0f + erfv);
}

// ---- w1 fp32 [C][H] -> plain bf16 transpose w1t[H][C] ----
__global__ void k_prep(const float* __restrict__ w1, unsigned short* __restrict__ w1t) {
  int i = blockIdx.x * blockDim.x + threadIdx.x;  // i = c*H + h over w1
  if (i < C_ * H_) {
    int c = i / H_, h = i % H_;
    w1t[h * C_ + c] = f2bf(w1[i]);
  }
}

// ---------------- fused scorer: scores = fc2(gelu(fc1(tokens))) ----------------
// Cooperative block, round-14 edition:
//  * staging roles swapped to (t=tid&15 token, s=tid>>4 chunk-pair) -> ds_write
//    lanes are byte-consecutive = conflict-free (round 13 had 16-way conflicts)
//  * depth-2 register prefetch (vvA holds group i+1, vvB issues i+2) -> load-use
//    distance > one full iteration, covering ~900cy HBM latency
// Fragment layout [kk][l4][t] is byte-identical to round 13 -> reads unchanged.
__global__ __launch_bounds__(256) void k_score(
    const float* __restrict__ tokens, const unsigned short* __restrict__ w1t,
    const float* __restrict__ b1, const float* __restrict__ w2,
    const float* __restrict__ b2, float* __restrict__ scores_out) {
  __shared__ unsigned short lds_a[2][8 * 64 * 8];  // 2 x 8KB bf16 A-fragments
  __shared__ float lds_c[4][16];                   // per-wave partial scores

  const int tid = threadIdx.x;
  const int lane = tid & 63;
  const int l15 = lane & 15;
  const int l4 = lane >> 4;
  const int w = tid >> 6;  // wave 0..3

  // W1 fragments for this wave's hidden blocks nb=2w (row0) and nb=2w+1 (row1)
  s16x8 bfr0[8], bfr1[8];
  const int row0 = (2 * w) * 16 + l15;
  const int row1 = row0 + 16;
#pragma unroll
  for (int kk = 0; kk < 8; ++kk) {
    bfr0[kk] = *reinterpret_cast<const s16x8*>(w1t + row0 * 256 + (l4 + 4 * kk) * 8);
    bfr1[kk] = *reinterpret_cast<const s16x8*>(w1t + row1 * 256 + (l4 + 4 * kk) * 8);
  }
  const float b1v0 = b1[row0], b1v1 = b1[row1];
  const float w2v0 = w2[row0], w2v1 = w2[row1];
  const float b2v = b2[0];

  // staging role: thread owns token t, fp32 chunk-pair s (16 consecutive floats)
  const int t = tid & 15;
  const int s = tid >> 4;
  const int g0 = blockIdx.x * GPB_;
  // this thread's global source for group g0: +i*4096 floats per group
  const float* tg = tokens + ((size_t)(g0 * 16 + t)) * 256 + s * 16;
  // this thread's two LDS chunk bases (ushort index): chunk c=2s+j at c*128+t*8
  const int lb0 = (2 * s) * 128 + t * 8;
  const int lb1 = lb0 + 128;

  f32x4 vvA[4], vvB[4];

  // prologue: stage group g0 into buffer 0, then issue loads for group g0+1
  {
#pragma unroll
    for (int q = 0; q < 4; ++q) vvA[q] = *reinterpret_cast<const f32x4*>(tg + 4 * q);
    u32x4 o0, o1;
    o0[0] = pk2(vvA[0][1], vvA[0][0]);
    o0[1] = pk2(vvA[0][3], vvA[0][2]);
    o0[2] = pk2(vvA[1][1], vvA[1][0]);
    o0[3] = pk2(vvA[1][3], vvA[1][2]);
    o1[0] = pk2(vvA[2][1], vvA[2][0]);
    o1[1] = pk2(vvA[2][3], vvA[2][2]);
    o1[2] = pk2(vvA[3][1], vvA[3][0]);
    o1[3] = pk2(vvA[3][3], vvA[3][2]);
    *reinterpret_cast<u32x4*>(&lds_a[0][lb0]) = o0;
    *reinterpret_cast<u32x4*>(&lds_a[0][lb1]) = o1;
    if (GPB_ > 1) {
#pragma unroll
      for (int q = 0; q < 4; ++q)
        vvA[q] = *reinterpret_cast<const f32x4*>(tg + 4096 + 4 * q);
    }
  }
  __syncthreads();

  for (int i = 0; i < GPB_; ++i) {
    const int g = g0 + i;
    const int cur = i & 1;
    // (1) issue loads for group i+2 (land ~1.5 iterations later)
    if (i + 2 < GPB_) {
      const float* p = tg + (size_t)(i + 2) * 4096;
#pragma unroll
      for (int q = 0; q < 4; ++q) vvB[q] = *reinterpret_cast<const f32x4*>(p + 4 * q);
    }

    // (2) compute: 16 MFMAs (8 kk x 2 nb), A from LDS, B from registers
    f32x4 acc0 = (f32x4){0.f, 0.f, 0.f, 0.f};
    f32x4 acc1 = (f32x4){0.f, 0.f, 0.f, 0.f};
#pragma unroll
    for (int kk = 0; kk < 8; ++kk) {
      s16x8 a = *reinterpret_cast<const s16x8*>(&lds_a[cur][(kk * 64 + lane) * 8]);
      acc0 = __builtin_amdgcn_mfma_f32_16x16x32_bf16(a, bfr0[kk], acc0, 0, 0, 0);
      acc1 = __builtin_amdgcn_mfma_f32_16x16x32_bf16(a, bfr1[kk], acc1, 0, 0, 0);
    }

    // (3) partial epilogue; reduce over l15 (hidden dim within wave's 2 blocks)
    float p4[4];
#pragma unroll
    for (int rr = 0; rr < 4; ++rr) {
      float sp = gelu_fast(acc0[rr] + b1v0) * w2v0 + gelu_fast(acc1[rr] + b1v1) * w2v1;
      sp += __shfl_xor(sp, 1);
      sp += __shfl_xor(sp, 2);
      sp += __shfl_xor(sp, 4);
      sp += __shfl_xor(sp, 8);
      p4[rr] = sp;  // score partial for token l4*4+rr
    }
    if (l15 == 0) {
#pragma unroll
      for (int rr = 0; rr < 4; ++rr) lds_c[w][l4 * 4 + rr] = p4[rr];
    }
    __syncthreads();  // (A) partials visible; lds_a[cur] reads done

    if (tid < 16) {
      scores_out[g * 16 + tid] =
          lds_c[0][tid] + lds_c[1][tid] + lds_c[2][tid] + lds_c[3][tid] + b2v;
    }
    // (4) write-late: pack group i+1 (vvA) into the other buffer — conflict-free
    if (i + 1 < GPB_) {
      u32x4 o0, o1;
      o0[0] = pk2(vvA[0][1], vvA[0][0]);
      o0[1] = pk2(vvA[0][3], vvA[0][2]);
      o0[2] = pk2(vvA[1][1], vvA[1][0]);
      o0[3] = pk2(vvA[1][3], vvA[1][2]);
      o1[0] = pk2(vvA[2][1], vvA[2][0]);
      o1[1] = pk2(vvA[2][3], vvA[2][2]);
      o1[2] = pk2(vvA[3][1], vvA[3][0]);
      o1[3] = pk2(vvA[3][3], vvA[3][2]);
      *reinterpret_cast<u32x4*>(&lds_a[cur ^ 1][lb0]) = o0;
      *reinterpret_cast<u32x4*>(&lds_a[cur ^ 1][lb1]) = o1;
    }
    __syncthreads();  // (B) staging complete; lds_c consumed
    // (5) rotate prefetch registers
#pragma unroll
    for (int q = 0; q < 4; ++q) vvA[q] = vvB[q];
  }
}

// ---------------- block-wide exclusive scan over 1024 threads ----------------
__device__ unsigned block_exscan_1024(unsigned v, volatile unsigned* wsum) {
  const int lane = threadIdx.x & 63;
  const int w = threadIdx.x >> 6;  // 0..15
  unsigned x = v;
#pragma unroll
  for (int d = 1; d < 64; d <<= 1) {
    unsigned t = __shfl_up(x, d);
    if (lane >= d) x += t;
  }
  if (lane == 63) wsum[w] = x;
  __syncthreads();
  if (threadIdx.x == 0) {
    unsigned s = 0;
    for (int i = 0; i < 16; ++i) {
      unsigned t = wsum[i];
      wsum[i] = s;
      s += t;
    }
  }
  __syncthreads();
  unsigned r = wsum[w] + x - v;  // exclusive
  __syncthreads();               // protect wsum for a subsequent call
  return r;
}

// ---------------- per-row top-K via radix select + stable compaction ----------------
__global__ __launch_bounds__(1024) void k_select(const float* __restrict__ scores_f,
                                                 int* __restrict__ kept,
                                                 float* __restrict__ out_idx) {
  __shared__ unsigned hist[256];
  __shared__ unsigned wsum[16];
  __shared__ unsigned sh_prefix, sh_rk;
  const int b = blockIdx.x;
  const int tid = threadIdx.x;
  const float* sp = scores_f + (size_t)b * N_;

  unsigned prefix = 0;
  unsigned rk = K_;  // elements still needed
  for (int pass = 0; pass < 4; ++pass) {
    const int shift = 24 - pass * 8;
    if (tid < 256) hist[tid] = 0;
    __syncthreads();
    const unsigned pmask = pass ? (0xFFFFFFFFu << (shift + 8)) : 0u;
    for (int i = tid; i < N_; i += 1024) {
      unsigned k = fkey(sp[i]);
      if ((k & pmask) == prefix) atomicAdd(&hist[(k >> shift) & 255u], 1u);
    }
    __syncthreads();
    // parallel bin search: suffix-sum via reversed block scan
    unsigned h = (tid < 256) ? hist[255 - tid] : 0u;
    unsigned s = block_exscan_1024(h, wsum);  // s = count of keys in bins > (255-tid)
    if (tid < 256 && s < rk && s + h >= rk) {
      sh_prefix = prefix | ((unsigned)(255 - tid) << shift);
      sh_rk = rk - s;
    }
    __syncthreads();
    prefix = sh_prefix;
    rk = sh_rk;
    __syncthreads();
  }
  const unsigned Tkey = prefix;   // K-th largest key
  const unsigned need = rk;       // how many ==Tkey to keep (lowest indices first)

  // stable compaction in index order; thread owns 16 consecutive indices
  const int i0 = tid * 16;
  unsigned neq = 0;
  for (int j = 0; j < 16; ++j) {
    unsigned k = fkey(sp[i0 + j]);
    neq += (k == Tkey);
  }
  unsigned eq_base = block_exscan_1024(neq, wsum);

  unsigned kcnt = 0;
  {
    unsigned eqr = eq_base;
    for (int j = 0; j < 16; ++j) {
      unsigned k = fkey(sp[i0 + j]);
      bool kp = (k > Tkey) || ((k == Tkey) && (eqr < need));
      eqr += (k == Tkey);
      kcnt += kp;
    }
  }
  unsigned pos = block_exscan_1024(kcnt, wsum);
  {
    unsigned eqr = eq_base;
    for (int j = 0; j < 16; ++j) {
      unsigned k = fkey(sp[i0 + j]);
      bool kp = (k > Tkey) || ((k == Tkey) && (eqr < need));
      eqr += (k == Tkey);
      if (kp) {
        kept[(size_t)b * K_ + pos] = i0 + j;
        out_idx[(size_t)b * K_ + pos] = (float)(i0 + j);
        ++pos;
      }
    }
  }
}

// ---------------- gather kept token rows (fp32 -> fp32) ----------------
__global__ __launch_bounds__(256) void k_gather(const float* __restrict__ tokens,
                                                const int* __restrict__ kept,
                                                float* __restrict__ outp) {
  const int wid = (blockIdx.x * blockDim.x + threadIdx.x) >> 6;  // one wave per row
  const int lane = threadIdx.x & 63;
  if (wid >= B_ * K_) return;
  const int b = wid / K_;
  const int idx = kept[wid];
  const f32x4 v = *reinterpret_cast<const f32x4*>(tokens + ((size_t)b * N_ + idx) * C_ + lane * 4);
  *reinterpret_cast<f32x4*>(outp + (size_t)wid * C_ + lane * 4) = v;
}

extern "C" void kernel_launch(void* const* d_in, const int* in_sizes, int n_in,
                              void* d_out, int out_size, void* d_ws, size_t ws_size,
                              hipStream_t stream) {
  const float* tokens = (const float*)d_in[0];
  const float* w1 = (const float*)d_in[1];
  const float* b1 = (const float*)d_in[2];
  const float* w2 = (const float*)d_in[3];
  const float* b2 = (const float*)d_in[4];

  float* out = (float*)d_out;
  float* out_pruned = out;                                  // B*K*C fp32
  float* out_idx = out + (size_t)B_ * K_ * C_;              // B*K fp32
  float* out_scores = out_idx + (size_t)B_ * K_;            // B*N fp32

  char* ws = (char*)d_ws;
  unsigned short* w1t = (unsigned short*)ws;                // 64 KB plain bf16 W1^T
  int* kept = (int*)(ws + 0x10000);                         // B*K int32

  k_prep<<<dim3((C_ * H_ + 255) / 256), dim3(256), 0, stream>>>(w1, w1t);
  k_score<<<dim3(NBLK_), dim3(256), 0, stream>>>(tokens, w1t, b1, w2, b2, out_scores);
  k_select<<<dim3(B_), dim3(1024), 0, stream>>>(out_scores, kept, out_idx);
  k_gather<<<dim3((B_ * K_ + 3) / 4), dim3(256), 0, stream>>>(tokens, kept, out_pruned);
}

// Round 15
// 169.385 us; speedup vs baseline: 1.0940x; 1.0940x over previous
//
#include <hip/hip_runtime.h>
#include <math.h>

#define B_ 16
#define N_ 16384
#define C_ 256
#define H_ 128
#define K_ 11468   // int(16384 * 0.7)
#define G_ ((B_ * N_) / 16)   // 16384 groups of 16 tokens
#define GPB_ 16               // groups per block
#define NBLK_ (G_ / GPB_)     // 1024 blocks

typedef __attribute__((ext_vector_type(8))) short s16x8;
typedef __attribute__((ext_vector_type(4))) float f32x4;
typedef __attribute__((ext_vector_type(4))) unsigned int u32x4;

__device__ __forceinline__ unsigned short f2bf(float f) {
  unsigned u = __builtin_bit_cast(unsigned, f);
  return (unsigned short)((u + 0x7FFFu + ((u >> 16) & 1u)) >> 16);  // RNE
}
// order-preserving map fp32 -> uint32 (no NaNs expected)
__device__ __forceinline__ unsigned fkey(float f) {
  unsigned u = __builtin_bit_cast(unsigned, f);
  return (u & 0x80000000u) ? ~u : (u | 0x80000000u);
}
// pack two fp32 to two bf16 (truncation) in one v_perm — same bits as rounds 4-14
__device__ __forceinline__ unsigned pk2(float hi, float lo) {
  return __builtin_amdgcn_perm(__builtin_bit_cast(unsigned, hi),
                               __builtin_bit_cast(unsigned, lo), 0x07060302u);
}

// branch-free GELU: Winitzki erf approx (max abs err ~1.2e-4), ~14 VALU ops.
__device__ __forceinline__ float gelu_fast(float h) {
  const float t = 0.5f * h * h;                 // z^2, z = h/sqrt(2)
  const float u = 0.147f * t;
  const float num = t * (1.2732395f + u);       // z^2*(4/pi + a z^2)
  const float den = 1.0f + u;
  const float r = num * __builtin_amdgcn_rcpf(den);
  const float e = __builtin_amdgcn_exp2f(r * -1.44269504f);   // exp(-r)
  const float s = __builtin_amdgcn_sqrtf(fmaxf(1.0f - e, 0.0f));
  const unsigned sgn = __builtin_bit_cast(unsigned, h) & 0x80000000u;
  const float erfv = __builtin_bit_cast(float, __builtin_bit_cast(unsigned, s) | sgn);
  return 0.5f * h * (1.0f + erfv);
}

// ---- w1 fp32 [C][H] -> plain bf16 transpose w1t[H][C] ----
__global__ void k_prep(const float* __restrict__ w1, unsigned short* __restrict__ w1t) {
  int i = blockIdx.x * blockDim.x + threadIdx.x;  // i = c*H + h over w1
  if (i < C_ * H_) {
    int c = i / H_, h = i % H_;
    w1t[h * C_ + c] = f2bf(w1[i]);
  }
}

// ---------------- fused scorer: scores = fc2(gelu(fc1(tokens))) ----------------
// Round-15 = round-13 structure (depth-1 prefetch, no register rotation) with
// ONE change: staging roles swapped to (t=tid&15 token, s=tid>>4 chunk-pair).
// ds_write slot = t%8 -> every 8 consecutive lanes hit 8 distinct bank-quads
// (the b128 floor), vs round 13's slot = sr (16-way serialization). Fragment
// layout [kk][l4][t] is byte-identical -> reads and scores unchanged.
__global__ __launch_bounds__(256) void k_score(
    const float* __restrict__ tokens, const unsigned short* __restrict__ w1t,
    const float* __restrict__ b1, const float* __restrict__ w2,
    const float* __restrict__ b2, float* __restrict__ scores_out) {
  __shared__ unsigned short lds_a[2][8 * 64 * 8];  // 2 x 8KB bf16 A-fragments
  __shared__ float lds_c[4][16];                   // per-wave partial scores

  const int tid = threadIdx.x;
  const int lane = tid & 63;
  const int l15 = lane & 15;
  const int l4 = lane >> 4;
  const int w = tid >> 6;  // wave 0..3

  // W1 fragments for this wave's hidden blocks nb=2w (row0) and nb=2w+1 (row1)
  s16x8 bfr0[8], bfr1[8];
  const int row0 = (2 * w) * 16 + l15;
  const int row1 = row0 + 16;
#pragma unroll
  for (int kk = 0; kk < 8; ++kk) {
    bfr0[kk] = *reinterpret_cast<const s16x8*>(w1t + row0 * 256 + (l4 + 4 * kk) * 8);
    bfr1[kk] = *reinterpret_cast<const s16x8*>(w1t + row1 * 256 + (l4 + 4 * kk) * 8);
  }
  const float b1v0 = b1[row0], b1v1 = b1[row1];
  const float w2v0 = w2[row0], w2v1 = w2[row1];
  const float b2v = b2[0];

  // staging role: thread owns token t, fp32 chunk-pair s (16 consecutive floats)
  const int t = tid & 15;
  const int s = tid >> 4;
  const int g0 = blockIdx.x * GPB_;
  const float* tg = tokens + ((size_t)(g0 * 16 + t)) * 256 + s * 16;
  // LDS chunk bases (ushort index): chunk c=2s+j lives at c*128 + t*8
  const int lb0 = (2 * s) * 128 + t * 8;
  const int lb1 = lb0 + 128;

  f32x4 vv[4];

  // prologue: stage group g0 into buffer 0
  {
#pragma unroll
    for (int q = 0; q < 4; ++q) vv[q] = *reinterpret_cast<const f32x4*>(tg + 4 * q);
    u32x4 o0, o1;
    o0[0] = pk2(vv[0][1], vv[0][0]);
    o0[1] = pk2(vv[0][3], vv[0][2]);
    o0[2] = pk2(vv[1][1], vv[1][0]);
    o0[3] = pk2(vv[1][3], vv[1][2]);
    o1[0] = pk2(vv[2][1], vv[2][0]);
    o1[1] = pk2(vv[2][3], vv[2][2]);
    o1[2] = pk2(vv[3][1], vv[3][0]);
    o1[3] = pk2(vv[3][3], vv[3][2]);
    *reinterpret_cast<u32x4*>(&lds_a[0][lb0]) = o0;
    *reinterpret_cast<u32x4*>(&lds_a[0][lb1]) = o1;
  }
  __syncthreads();

  int cur = 0;
  for (int i = 0; i < GPB_; ++i) {
    const int g = g0 + i;
    // (1) issue next group's loads EARLY; they land during MFMAs + barriers
    if (i + 1 < GPB_) {
      const float* p = tg + (size_t)(i + 1) * 4096;
#pragma unroll
      for (int q = 0; q < 4; ++q) vv[q] = *reinterpret_cast<const f32x4*>(p + 4 * q);
    }

    // (2) compute: 16 MFMAs (8 kk x 2 nb), A from LDS, B from registers
    f32x4 acc0 = (f32x4){0.f, 0.f, 0.f, 0.f};
    f32x4 acc1 = (f32x4){0.f, 0.f, 0.f, 0.f};
#pragma unroll
    for (int kk = 0; kk < 8; ++kk) {
      s16x8 a = *reinterpret_cast<const s16x8*>(&lds_a[cur][(kk * 64 + lane) * 8]);
      acc0 = __builtin_amdgcn_mfma_f32_16x16x32_bf16(a, bfr0[kk], acc0, 0, 0, 0);
      acc1 = __builtin_amdgcn_mfma_f32_16x16x32_bf16(a, bfr1[kk], acc1, 0, 0, 0);
    }

    // (3) partial epilogue; reduce over l15
    float p4[4];
#pragma unroll
    for (int rr = 0; rr < 4; ++rr) {
      float sp = gelu_fast(acc0[rr] + b1v0) * w2v0 + gelu_fast(acc1[rr] + b1v1) * w2v1;
      sp += __shfl_xor(sp, 1);
      sp += __shfl_xor(sp, 2);
      sp += __shfl_xor(sp, 4);
      sp += __shfl_xor(sp, 8);
      p4[rr] = sp;  // score partial for token l4*4+rr
    }
    if (l15 == 0) {
#pragma unroll
      for (int rr = 0; rr < 4; ++rr) lds_c[w][l4 * 4 + rr] = p4[rr];
    }
    __syncthreads();  // (A) partials visible; lds_a[cur] reads done

    if (tid < 16) {
      scores_out[g * 16 + tid] =
          lds_c[0][tid] + lds_c[1][tid] + lds_c[2][tid] + lds_c[3][tid] + b2v;
    }
    // (4) write-late: pack group i+1 into the other buffer — bank-quad optimal
    if (i + 1 < GPB_) {
      u32x4 o0, o1;
      o0[0] = pk2(vv[0][1], vv[0][0]);
      o0[1] = pk2(vv[0][3], vv[0][2]);
      o0[2] = pk2(vv[1][1], vv[1][0]);
      o0[3] = pk2(vv[1][3], vv[1][2]);
      o1[0] = pk2(vv[2][1], vv[2][0]);
      o1[1] = pk2(vv[2][3], vv[2][2]);
      o1[2] = pk2(vv[3][1], vv[3][0]);
      o1[3] = pk2(vv[3][3], vv[3][2]);
      *reinterpret_cast<u32x4*>(&lds_a[cur ^ 1][lb0]) = o0;
      *reinterpret_cast<u32x4*>(&lds_a[cur ^ 1][lb1]) = o1;
    }
    __syncthreads();  // (B) staging complete; lds_c consumed
    cur ^= 1;
  }
}

// ---------------- block-wide exclusive scan over 1024 threads ----------------
__device__ unsigned block_exscan_1024(unsigned v, volatile unsigned* wsum) {
  const int lane = threadIdx.x & 63;
  const int w = threadIdx.x >> 6;  // 0..15
  unsigned x = v;
#pragma unroll
  for (int d = 1; d < 64; d <<= 1) {
    unsigned t = __shfl_up(x, d);
    if (lane >= d) x += t;
  }
  if (lane == 63) wsum[w] = x;
  __syncthreads();
  if (threadIdx.x == 0) {
    unsigned s = 0;
    for (int i = 0; i < 16; ++i) {
      unsigned t = wsum[i];
      wsum[i] = s;
      s += t;
    }
  }
  __syncthreads();
  unsigned r = wsum[w] + x - v;  // exclusive
  __syncthreads();               // protect wsum for a subsequent call
  return r;
}

// ---------------- per-row top-K via radix select + stable compaction ----------------
__global__ __launch_bounds__(1024) void k_select(const float* __restrict__ scores_f,
                                                 int* __restrict__ kept,
                                                 float* __restrict__ out_idx) {
  __shared__ unsigned hist[256];
  __shared__ unsigned wsum[16];
  __shared__ unsigned sh_prefix, sh_rk;
  const int b = blockIdx.x;
  const int tid = threadIdx.x;
  const float* sp = scores_f + (size_t)b * N_;

  unsigned prefix = 0;
  unsigned rk = K_;  // elements still needed
  for (int pass = 0; pass < 4; ++pass) {
    const int shift = 24 - pass * 8;
    if (tid < 256) hist[tid] = 0;
    __syncthreads();
    const unsigned pmask = pass ? (0xFFFFFFFFu << (shift + 8)) : 0u;
    for (int i = tid; i < N_; i += 1024) {
      unsigned k = fkey(sp[i]);
      if ((k & pmask) == prefix) atomicAdd(&hist[(k >> shift) & 255u], 1u);
    }
    __syncthreads();
    // parallel bin search: suffix-sum via reversed block scan
    unsigned h = (tid < 256) ? hist[255 - tid] : 0u;
    unsigned s = block_exscan_1024(h, wsum);  // s = count of keys in bins > (255-tid)
    if (tid < 256 && s < rk && s + h >= rk) {
      sh_prefix = prefix | ((unsigned)(255 - tid) << shift);
      sh_rk = rk - s;
    }
    __syncthreads();
    prefix = sh_prefix;
    rk = sh_rk;
    __syncthreads();
  }
  const unsigned Tkey = prefix;   // K-th largest key
  const unsigned need = rk;       // how many ==Tkey to keep (lowest indices first)

  // stable compaction in index order; thread owns 16 consecutive indices
  const int i0 = tid * 16;
  unsigned neq = 0;
  for (int j = 0; j < 16; ++j) {
    unsigned k = fkey(sp[i0 + j]);
    neq += (k == Tkey);
  }
  unsigned eq_base = block_exscan_1024(neq, wsum);

  unsigned kcnt = 0;
  {
    unsigned eqr = eq_base;
    for (int j = 0; j < 16; ++j) {
      unsigned k = fkey(sp[i0 + j]);
      bool kp = (k > Tkey) || ((k == Tkey) && (eqr < need));
      eqr += (k == Tkey);
      kcnt += kp;
    }
  }
  unsigned pos = block_exscan_1024(kcnt, wsum);
  {
    unsigned eqr = eq_base;
    for (int j = 0; j < 16; ++j) {
      unsigned k = fkey(sp[i0 + j]);
      bool kp = (k > Tkey) || ((k == Tkey) && (eqr < need));
      eqr += (k == Tkey);
      if (kp) {
        kept[(size_t)b * K_ + pos] = i0 + j;
        out_idx[(size_t)b * K_ + pos] = (float)(i0 + j);
        ++pos;
      }
    }
  }
}

// ---------------- gather kept token rows (fp32 -> fp32) ----------------
__global__ __launch_bounds__(256) void k_gather(const float* __restrict__ tokens,
                                                const int* __restrict__ kept,
                                                float* __restrict__ outp) {
  const int wid = (blockIdx.x * blockDim.x + threadIdx.x) >> 6;  // one wave per row
  const int lane = threadIdx.x & 63;
  if (wid >= B_ * K_) return;
  const int b = wid / K_;
  const int idx = kept[wid];
  const f32x4 v = *reinterpret_cast<const f32x4*>(tokens + ((size_t)b * N_ + idx) * C_ + lane * 4);
  *reinterpret_cast<f32x4*>(outp + (size_t)wid * C_ + lane * 4) = v;
}

extern "C" void kernel_launch(void* const* d_in, const int* in_sizes, int n_in,
                              void* d_out, int out_size, void* d_ws, size_t ws_size,
                              hipStream_t stream) {
  const float* tokens = (const float*)d_in[0];
  const float* w1 = (const float*)d_in[1];
  const float* b1 = (const float*)d_in[2];
  const float* w2 = (const float*)d_in[3];
  const float* b2 = (const float*)d_in[4];

  float* out = (float*)d_out;
  float* out_pruned = out;                                  // B*K*C fp32
  float* out_idx = out + (size_t)B_ * K_ * C_;              // B*K fp32
  float* out_scores = out_idx + (size_t)B_ * K_;            // B*N fp32

  char* ws = (char*)d_ws;
  unsigned short* w1t = (unsigned short*)ws;                // 64 KB plain bf16 W1^T
  int* kept = (int*)(ws + 0x10000);                         // B*K int32

  k_prep<<<dim3((C_ * H_ + 255) / 256), dim3(256), 0, stream>>>(w1, w1t);
  k_score<<<dim3(NBLK_), dim3(256), 0, stream>>>(tokens, w1t, b1, w2, b2, out_scores);
  k_select<<<dim3(B_), dim3(1024), 0, stream>>>(out_scores, kept, out_idx);
  k_gather<<<dim3((B_ * K_ + 3) / 4), dim3(256), 0, stream>>>(tokens, kept, out_pruned);
}

// Round 16
// 169.339 us; speedup vs baseline: 1.0943x; 1.0003x over previous
//
#include <hip/hip_runtime.h>
#include <math.h>

#define B_ 16
#define N_ 16384
#define C_ 256
#define H_ 128
#define K_ 11468   // int(16384 * 0.7)
#define G_ ((B_ * N_) / 16)   // 16384 groups of 16 tokens
#define GPB_ 16               // groups per block
#define NBLK_ (G_ / GPB_)     // 1024 blocks

typedef __attribute__((ext_vector_type(8))) short s16x8;
typedef __attribute__((ext_vector_type(4))) float f32x4;
typedef __attribute__((ext_vector_type(4))) unsigned int u32x4;

__device__ __forceinline__ unsigned short f2bf(float f) {
  unsigned u = __builtin_bit_cast(unsigned, f);
  return (unsigned short)((u + 0x7FFFu + ((u >> 16) & 1u)) >> 16);  // RNE
}
// order-preserving map fp32 -> uint32 (no NaNs expected)
__device__ __forceinline__ unsigned fkey(float f) {
  unsigned u = __builtin_bit_cast(unsigned, f);
  return (u & 0x80000000u) ? ~u : (u | 0x80000000u);
}
// pack two fp32 to two bf16 (truncation) in one v_perm — same bits as rounds 4-15
__device__ __forceinline__ unsigned pk2(float hi, float lo) {
  return __builtin_amdgcn_perm(__builtin_bit_cast(unsigned, hi),
                               __builtin_bit_cast(unsigned, lo), 0x07060302u);
}

// LDS-only barrier: orders LDS ops across the workgroup WITHOUT draining
// outstanding global loads (unlike __syncthreads(), which emits
// s_waitcnt vmcnt(0) lgkmcnt(0) and kills prefetch overlap — m97 lesson).
#define LDS_BARRIER()                                     \
  do {                                                    \
    asm volatile("s_waitcnt lgkmcnt(0)" ::: "memory");    \
    __builtin_amdgcn_s_barrier();                         \
  } while (0)

// branch-free GELU: Winitzki erf approx (max abs err ~1.2e-4), ~14 VALU ops.
__device__ __forceinline__ float gelu_fast(float h) {
  const float t = 0.5f * h * h;                 // z^2, z = h/sqrt(2)
  const float u = 0.147f * t;
  const float num = t * (1.2732395f + u);       // z^2*(4/pi + a z^2)
  const float den = 1.0f + u;
  const float r = num * __builtin_amdgcn_rcpf(den);
  const float e = __builtin_amdgcn_exp2f(r * -1.44269504f);   // exp(-r)
  const float s = __builtin_amdgcn_sqrtf(fmaxf(1.0f - e, 0.0f));
  const unsigned sgn = __builtin_bit_cast(unsigned, h) & 0x80000000u;
  const float erfv = __builtin_bit_cast(float, __builtin_bit_cast(unsigned, s) | sgn);
  return 0.5f * h * (1.0f + erfv);
}

// ---- w1 fp32 [C][H] -> plain bf16 transpose w1t[H][C] ----
__global__ void k_prep(const float* __restrict__ w1, unsigned short* __restrict__ w1t) {
  int i = blockIdx.x * blockDim.x + threadIdx.x;  // i = c*H + h over w1
  if (i < C_ * H_) {
    int c = i / H_, h = i % H_;
    w1t[h * C_ + c] = f2bf(w1[i]);
  }
}

// ---------------- fused scorer: scores = fc2(gelu(fc1(tokens))) ----------------
// Round-16 = round-15 with ONE change: the three __syncthreads() become
// LDS-only barriers (lgkmcnt drain, NO vmcnt drain). The step-1 prefetch loads
// now stay in flight across barrier A and land at step 4's pack — full-iteration
// (~900cy+) load->use distance without extra registers.
__global__ __launch_bounds__(256) void k_score(
    const float* __restrict__ tokens, const unsigned short* __restrict__ w1t,
    const float* __restrict__ b1, const float* __restrict__ w2,
    const float* __restrict__ b2, float* __restrict__ scores_out) {
  __shared__ unsigned short lds_a[2][8 * 64 * 8];  // 2 x 8KB bf16 A-fragments
  __shared__ float lds_c[4][16];                   // per-wave partial scores

  const int tid = threadIdx.x;
  const int lane = tid & 63;
  const int l15 = lane & 15;
  const int l4 = lane >> 4;
  const int w = tid >> 6;  // wave 0..3

  // W1 fragments for this wave's hidden blocks nb=2w (row0) and nb=2w+1 (row1)
  s16x8 bfr0[8], bfr1[8];
  const int row0 = (2 * w) * 16 + l15;
  const int row1 = row0 + 16;
#pragma unroll
  for (int kk = 0; kk < 8; ++kk) {
    bfr0[kk] = *reinterpret_cast<const s16x8*>(w1t + row0 * 256 + (l4 + 4 * kk) * 8);
    bfr1[kk] = *reinterpret_cast<const s16x8*>(w1t + row1 * 256 + (l4 + 4 * kk) * 8);
  }
  const float b1v0 = b1[row0], b1v1 = b1[row1];
  const float w2v0 = w2[row0], w2v1 = w2[row1];
  const float b2v = b2[0];

  // staging role: thread owns token t, fp32 chunk-pair s (16 consecutive floats)
  const int t = tid & 15;
  const int s = tid >> 4;
  const int g0 = blockIdx.x * GPB_;
  const float* tg = tokens + ((size_t)(g0 * 16 + t)) * 256 + s * 16;
  // LDS chunk bases (ushort index): chunk c=2s+j lives at c*128 + t*8
  const int lb0 = (2 * s) * 128 + t * 8;
  const int lb1 = lb0 + 128;

  f32x4 vv[4];

  // prologue: stage group g0 into buffer 0
  {
#pragma unroll
    for (int q = 0; q < 4; ++q) vv[q] = *reinterpret_cast<const f32x4*>(tg + 4 * q);
    u32x4 o0, o1;
    o0[0] = pk2(vv[0][1], vv[0][0]);
    o0[1] = pk2(vv[0][3], vv[0][2]);
    o0[2] = pk2(vv[1][1], vv[1][0]);
    o0[3] = pk2(vv[1][3], vv[1][2]);
    o1[0] = pk2(vv[2][1], vv[2][0]);
    o1[1] = pk2(vv[2][3], vv[2][2]);
    o1[2] = pk2(vv[3][1], vv[3][0]);
    o1[3] = pk2(vv[3][3], vv[3][2]);
    *reinterpret_cast<u32x4*>(&lds_a[0][lb0]) = o0;
    *reinterpret_cast<u32x4*>(&lds_a[0][lb1]) = o1;
  }
  LDS_BARRIER();

  int cur = 0;
  for (int i = 0; i < GPB_; ++i) {
    const int g = g0 + i;
    // (1) issue next group's loads EARLY; they stay in flight past barrier A
    if (i + 1 < GPB_) {
      const float* p = tg + (size_t)(i + 1) * 4096;
#pragma unroll
      for (int q = 0; q < 4; ++q) vv[q] = *reinterpret_cast<const f32x4*>(p + 4 * q);
    }

    // (2) compute: 16 MFMAs (8 kk x 2 nb), A from LDS, B from registers
    f32x4 acc0 = (f32x4){0.f, 0.f, 0.f, 0.f};
    f32x4 acc1 = (f32x4){0.f, 0.f, 0.f, 0.f};
#pragma unroll
    for (int kk = 0; kk < 8; ++kk) {
      s16x8 a = *reinterpret_cast<const s16x8*>(&lds_a[cur][(kk * 64 + lane) * 8]);
      acc0 = __builtin_amdgcn_mfma_f32_16x16x32_bf16(a, bfr0[kk], acc0, 0, 0, 0);
      acc1 = __builtin_amdgcn_mfma_f32_16x16x32_bf16(a, bfr1[kk], acc1, 0, 0, 0);
    }

    // (3) partial epilogue; reduce over l15
    float p4[4];
#pragma unroll
    for (int rr = 0; rr < 4; ++rr) {
      float sp = gelu_fast(acc0[rr] + b1v0) * w2v0 + gelu_fast(acc1[rr] + b1v1) * w2v1;
      sp += __shfl_xor(sp, 1);
      sp += __shfl_xor(sp, 2);
      sp += __shfl_xor(sp, 4);
      sp += __shfl_xor(sp, 8);
      p4[rr] = sp;  // score partial for token l4*4+rr
    }
    if (l15 == 0) {
#pragma unroll
      for (int rr = 0; rr < 4; ++rr) lds_c[w][l4 * 4 + rr] = p4[rr];
    }
    LDS_BARRIER();  // (A) partials visible; lds_a[cur] reads done; loads NOT drained

    if (tid < 16) {
      scores_out[g * 16 + tid] =
          lds_c[0][tid] + lds_c[1][tid] + lds_c[2][tid] + lds_c[3][tid] + b2v;
    }
    // (4) write-late: pack group i+1 into the other buffer (compiler inserts the
    // minimal vmcnt wait for vv right here — the only place it's needed)
    if (i + 1 < GPB_) {
      u32x4 o0, o1;
      o0[0] = pk2(vv[0][1], vv[0][0]);
      o0[1] = pk2(vv[0][3], vv[0][2]);
      o0[2] = pk2(vv[1][1], vv[1][0]);
      o0[3] = pk2(vv[1][3], vv[1][2]);
      o1[0] = pk2(vv[2][1], vv[2][0]);
      o1[1] = pk2(vv[2][3], vv[2][2]);
      o1[2] = pk2(vv[3][1], vv[3][0]);
      o1[3] = pk2(vv[3][3], vv[3][2]);
      *reinterpret_cast<u32x4*>(&lds_a[cur ^ 1][lb0]) = o0;
      *reinterpret_cast<u32x4*>(&lds_a[cur ^ 1][lb1]) = o1;
    }
    LDS_BARRIER();  // (B) staging complete; lds_c consumed
    cur ^= 1;
  }
}

// ---------------- block-wide exclusive scan over 1024 threads ----------------
__device__ unsigned block_exscan_1024(unsigned v, volatile unsigned* wsum) {
  const int lane = threadIdx.x & 63;
  const int w = threadIdx.x >> 6;  // 0..15
  unsigned x = v;
#pragma unroll
  for (int d = 1; d < 64; d <<= 1) {
    unsigned t = __shfl_up(x, d);
    if (lane >= d) x += t;
  }
  if (lane == 63) wsum[w] = x;
  __syncthreads();
  if (threadIdx.x == 0) {
    unsigned s = 0;
    for (int i = 0; i < 16; ++i) {
      unsigned t = wsum[i];
      wsum[i] = s;
      s += t;
    }
  }
  __syncthreads();
  unsigned r = wsum[w] + x - v;  // exclusive
  __syncthreads();               // protect wsum for a subsequent call
  return r;
}

// ---------------- per-row top-K via radix select + stable compaction ----------------
__global__ __launch_bounds__(1024) void k_select(const float* __restrict__ scores_f,
                                                 int* __restrict__ kept,
                                                 float* __restrict__ out_idx) {
  __shared__ unsigned hist[256];
  __shared__ unsigned wsum[16];
  __shared__ unsigned sh_prefix, sh_rk;
  const int b = blockIdx.x;
  const int tid = threadIdx.x;
  const float* sp = scores_f + (size_t)b * N_;

  unsigned prefix = 0;
  unsigned rk = K_;  // elements still needed
  for (int pass = 0; pass < 4; ++pass) {
    const int shift = 24 - pass * 8;
    if (tid < 256) hist[tid] = 0;
    __syncthreads();
    const unsigned pmask = pass ? (0xFFFFFFFFu << (shift + 8)) : 0u;
    for (int i = tid; i < N_; i += 1024) {
      unsigned k = fkey(sp[i]);
      if ((k & pmask) == prefix) atomicAdd(&hist[(k >> shift) & 255u], 1u);
    }
    __syncthreads();
    // parallel bin search: suffix-sum via reversed block scan
    unsigned h = (tid < 256) ? hist[255 - tid] : 0u;
    unsigned s = block_exscan_1024(h, wsum);  // s = count of keys in bins > (255-tid)
    if (tid < 256 && s < rk && s + h >= rk) {
      sh_prefix = prefix | ((unsigned)(255 - tid) << shift);
      sh_rk = rk - s;
    }
    __syncthreads();
    prefix = sh_prefix;
    rk = sh_rk;
    __syncthreads();
  }
  const unsigned Tkey = prefix;   // K-th largest key
  const unsigned need = rk;       // how many ==Tkey to keep (lowest indices first)

  // stable compaction in index order; thread owns 16 consecutive indices
  const int i0 = tid * 16;
  unsigned neq = 0;
  for (int j = 0; j < 16; ++j) {
    unsigned k = fkey(sp[i0 + j]);
    neq += (k == Tkey);
  }
  unsigned eq_base = block_exscan_1024(neq, wsum);

  unsigned kcnt = 0;
  {
    unsigned eqr = eq_base;
    for (int j = 0; j < 16; ++j) {
      unsigned k = fkey(sp[i0 + j]);
      bool kp = (k > Tkey) || ((k == Tkey) && (eqr < need));
      eqr += (k == Tkey);
      kcnt += kp;
    }
  }
  unsigned pos = block_exscan_1024(kcnt, wsum);
  {
    unsigned eqr = eq_base;
    for (int j = 0; j < 16; ++j) {
      unsigned k = fkey(sp[i0 + j]);
      bool kp = (k > Tkey) || ((k == Tkey) && (eqr < need));
      eqr += (k == Tkey);
      if (kp) {
        kept[(size_t)b * K_ + pos] = i0 + j;
        out_idx[(size_t)b * K_ + pos] = (float)(i0 + j);
        ++pos;
      }
    }
  }
}

// ---------------- gather kept token rows (fp32 -> fp32) ----------------
__global__ __launch_bounds__(256) void k_gather(const float* __restrict__ tokens,
                                                const int* __restrict__ kept,
                                                float* __restrict__ outp) {
  const int wid = (blockIdx.x * blockDim.x + threadIdx.x) >> 6;  // one wave per row
  const int lane = threadIdx.x & 63;
  if (wid >= B_ * K_) return;
  const int b = wid / K_;
  const int idx = kept[wid];
  const f32x4 v = *reinterpret_cast<const f32x4*>(tokens + ((size_t)b * N_ + idx) * C_ + lane * 4);
  *reinterpret_cast<f32x4*>(outp + (size_t)wid * C_ + lane * 4) = v;
}

extern "C" void kernel_launch(void* const* d_in, const int* in_sizes, int n_in,
                              void* d_out, int out_size, void* d_ws, size_t ws_size,
                              hipStream_t stream) {
  const float* tokens = (const float*)d_in[0];
  const float* w1 = (const float*)d_in[1];
  const float* b1 = (const float*)d_in[2];
  const float* w2 = (const float*)d_in[3];
  const float* b2 = (const float*)d_in[4];

  float* out = (float*)d_out;
  float* out_pruned = out;                                  // B*K*C fp32
  float* out_idx = out + (size_t)B_ * K_ * C_;              // B*K fp32
  float* out_scores = out_idx + (size_t)B_ * K_;            // B*N fp32

  char* ws = (char*)d_ws;
  unsigned short* w1t = (unsigned short*)ws;                // 64 KB plain bf16 W1^T
  int* kept = (int*)(ws + 0x10000);                         // B*K int32

  k_prep<<<dim3((C_ * H_ + 255) / 256), dim3(256), 0, stream>>>(w1, w1t);
  k_score<<<dim3(NBLK_), dim3(256), 0, stream>>>(tokens, w1t, b1, w2, b2, out_scores);
  k_select<<<dim3(B_), dim3(1024), 0, stream>>>(out_scores, kept, out_idx);
  k_gather<<<dim3((B_ * K_ + 3) / 4), dim3(256), 0, stream>>>(tokens, kept, out_pruned);
}